// Round 9
// baseline (2137.814 us; speedup 1.0000x reference)
//
#include <hip/hip_runtime.h>

typedef unsigned short u16;
typedef unsigned int u32;
typedef __attribute__((ext_vector_type(8))) short bf16x8;
typedef __attribute__((ext_vector_type(4))) float f32x4;

#define N_NODES 20000
#define N_EDGES 160000
#define DDIM    1000
#define KP      1024            // padded K / row stride (elements)
#define SP      41200000        // node-buffer spacing (bytes)

__device__ __forceinline__ float b2f(u16 u) {
    union { u32 i; float f; } v; v.i = ((u32)u) << 16; return v.f;
}
__device__ __forceinline__ u16 f2b(float f) {
    union { float f; u32 i; } v; v.f = f;
    u32 r = v.i + 0x7FFFu + ((v.i >> 16) & 1u);
    return (u16)(r >> 16);
}
__device__ __forceinline__ u32 pack2(float a, float b) {
    return (u32)f2b(a) | ((u32)f2b(b) << 16);
}
__device__ __forceinline__ f32x4 mfma16(bf16x8 a, bf16x8 b, f32x4 c) {
    return __builtin_amdgcn_mfma_f32_16x16x32_bf16(a, b, c, 0, 0, 0);
}
__device__ __forceinline__ float sigmoidf_(float x) { return 1.0f / (1.0f + expf(-x)); }

// async global->LDS DMA, 16 B per lane; lds dest = wave-uniform base + lane*16
__device__ __forceinline__ void gl2lds16(const u16* g, u16* l) {
    __builtin_amdgcn_global_load_lds(
        (const __attribute__((address_space(1))) u32*)g,
        (__attribute__((address_space(3))) u32*)l, 16, 0, 0);
}

// ---------------------------------------------------------------------------
// fp32 [rows][1000] -> bf16 [rows][1024], zero-padded cols. One block per row.
// ---------------------------------------------------------------------------
__global__ __launch_bounds__(256) void cvt_rows(const float* __restrict__ in,
                                                u16* __restrict__ out) {
    int r = blockIdx.x, c = threadIdx.x * 4;
    u32 o[2] = {0, 0};
    if (c < DDIM) {
        float4 v = *(const float4*)(in + (size_t)r * DDIM + c);
        o[0] = pack2(v.x, v.y); o[1] = pack2(v.z, v.w);
    }
    *(uint2*)(out + (size_t)r * KP + c) = *(const uint2*)o;
}

// ---------------------------------------------------------------------------
// Stacked GRU weights: wcat[g][n][0:1024) = wih[g*1000+n][:], zero-pad;
//                      wcat[g][n][1024:2048) = whh[g*1000+n][:], zero-pad.
// ---------------------------------------------------------------------------
__global__ __launch_bounds__(256) void cvt_wcat(const float* __restrict__ wih,
                                                const float* __restrict__ whh,
                                                u16* __restrict__ wcat) {
    int r = blockIdx.x;                  // 0..2999
    int g = r / 1000, n = r - g * 1000;
    int c = threadIdx.x * 4;             // 0..1020
    u16* dst = wcat + ((size_t)g * 1024 + n) * 2048;
    u32 o[2] = {0, 0};
    if (c < DDIM) {
        float4 v = *(const float4*)(wih + (size_t)r * DDIM + c);
        o[0] = pack2(v.x, v.y); o[1] = pack2(v.z, v.w);
    }
    *(uint2*)(dst + c) = *(const uint2*)o;
    o[0] = 0; o[1] = 0;
    if (c < DDIM) {
        float4 v = *(const float4*)(whh + (size_t)r * DDIM + c);
        o[0] = pack2(v.x, v.y); o[1] = pack2(v.z, v.w);
    }
    *(uint2*)(dst + 1024 + c) = *(const uint2*)o;
}

// ---------------------------------------------------------------------------
// weight[l] fp32 [k<1000][n<1000] -> Wt bf16 [n<1024][k<1024], zero-padded.
// ---------------------------------------------------------------------------
__global__ __launch_bounds__(256) void transpose_w(const float* __restrict__ W,
                                                   u16* __restrict__ Wt) {
    __shared__ u16 t[32][33];
    int l = blockIdx.z;
    int nb = blockIdx.x * 32, kb = blockIdx.y * 32;
    int x = threadIdx.x, y = threadIdx.y;   // block (32, 8)
    const float* Wl = W + (size_t)l * 1000000;
    u16* Wtl = Wt + (size_t)l * (KP * KP);
    for (int i = 0; i < 32; i += 8) {
        int k = kb + y + i, n = nb + x;
        t[y + i][x] = (k < DDIM && n < DDIM) ? f2b(Wl[(size_t)k * DDIM + n]) : (u16)0;
    }
    __syncthreads();
    for (int i = 0; i < 32; i += 8) {
        int n = nb + y + i, k = kb + x;
        Wtl[(size_t)n * KP + k] = t[x][y + i];
    }
}

// ---------------------------------------------------------------------------
// CSR build (edge list constant): count -> scan -> fill
// ---------------------------------------------------------------------------
__global__ __launch_bounds__(256) void count_edges(const int* __restrict__ ei,
                                                   int* __restrict__ cnt) {
    int e = blockIdx.x * 256 + threadIdx.x;
    if (e < N_EDGES) atomicAdd(&cnt[ei[N_EDGES + e]], 1);
}

__global__ __launch_bounds__(1024) void scan_offsets(const int* __restrict__ cnt,
                                                     int* __restrict__ ofs) {
    __shared__ int s[1024];
    const int CH = 20;
    int t = threadIdx.x;
    int base = t * CH;
    int loc[CH];
    int sum = 0;
    for (int j = 0; j < CH; j++) {
        int i = base + j;
        loc[j] = sum;
        sum += (i < N_NODES) ? cnt[i] : 0;
    }
    s[t] = sum;
    __syncthreads();
    for (int d = 1; d < 1024; d <<= 1) {
        int v = (t >= d) ? s[t - d] : 0;
        __syncthreads();
        s[t] += v;
        __syncthreads();
    }
    int excl = s[t] - sum;
    for (int j = 0; j < CH; j++) {
        int i = base + j;
        if (i < N_NODES) ofs[i] = excl + loc[j];
    }
    if (t == 0) ofs[N_NODES] = N_EDGES;
}

__global__ __launch_bounds__(256) void fill_buckets(const int* __restrict__ ei,
                                                    const int* __restrict__ ofs,
                                                    int* __restrict__ cur,
                                                    int* __restrict__ bkt) {
    int e = blockIdx.x * 256 + threadIdx.x;
    if (e >= N_EDGES) return;
    int d = ei[N_EDGES + e];
    int pos = atomicAdd(&cur[d], 1);
    bkt[ofs[d] + pos] = e;
}

// ---------------------------------------------------------------------------
// agg[node] = sum_{e: dst=node} m[src(e)] * ew[e] — one block/node, no atomics
// ---------------------------------------------------------------------------
__global__ __launch_bounds__(256) void node_agg(const int* __restrict__ ei,
                                                const float* __restrict__ ew,
                                                const int* __restrict__ ofs,
                                                const int* __restrict__ bkt,
                                                const u16* __restrict__ m,
                                                u16* __restrict__ agg) {
    __shared__ int   s_src[64];
    __shared__ float s_w[64];
    int node = blockIdx.x;
    int t = threadIdx.x;                 // t<250 owns features [4t, 4t+4)
    int beg = ofs[node], end = ofs[node + 1];
    float4 acc = {0.f, 0.f, 0.f, 0.f};
    for (int cb = beg; cb < end; cb += 64) {
        int n = min(64, end - cb);
        if (t < n) {
            int e = bkt[cb + t];
            s_src[t] = ei[e];
            s_w[t]   = ew[e];
        }
        __syncthreads();
        if (t < 250) {
            for (int j = 0; j < n; j++) {
                int src = s_src[j];
                float w = s_w[j];
                uint2 v = *(const uint2*)(m + (size_t)src * KP + t * 4);
                const u16* p = (const u16*)&v;
                acc.x += b2f(p[0]) * w;
                acc.y += b2f(p[1]) * w;
                acc.z += b2f(p[2]) * w;
                acc.w += b2f(p[3]) * w;
            }
        }
        __syncthreads();
    }
    if (t < 250) {
        u32 o[2] = {pack2(acc.x, acc.y), pack2(acc.z, acc.w)};
        *(uint2*)(agg + (size_t)node * KP + t * 4) = *(const uint2*)o;
    }
}

// ---------------------------------------------------------------------------
// C[m<20000][n<1000] = A[m][k<1024] @ Bt[n][k<1024]^T  (bf16, fp32 acc)
// 128x128 tile, BK=64, XOR-swizzled staging (conflict-free ds_read_b128).
// ---------------------------------------------------------------------------
__global__ __launch_bounds__(256) void gemm_bt(const u16* __restrict__ A,
                                               const u16* __restrict__ Bt,
                                               u16* __restrict__ C) {
    __shared__ u16 S[16384];             // Sa [128][64] @0, Sb @8192 (u16 idx)
    int tid = threadIdx.x;
    int lane = tid & 63, wave = tid >> 6;
    int wr = wave >> 1, wc = wave & 1;
    int bid = blockIdx.x;
    int m0 = (bid >> 3) * 128, n0 = (bid & 7) * 128;

    // staging map: LDS slot c (row=c>>3, s=c&7) <- global chunk kc = s^(row&7)
    int aoff[4], boff[4];
#pragma unroll
    for (int i = 0; i < 4; i++) {
        int c = tid + 256 * i;
        int row = c >> 3, sl = c & 7;
        int kc = sl ^ (row & 7);
        aoff[i] = (m0 + row) * KP + kc * 8;
        boff[i] = (n0 + row) * KP + kc * 8;
    }
    f32x4 acc[4][4] = {};
    int fr = lane & 15, q = lane >> 4, sw = fr & 7;

    for (int k0 = 0; k0 < KP; k0 += 64) {
#pragma unroll
        for (int i = 0; i < 4; i++) {
            gl2lds16(A + aoff[i] + k0, &S[tid * 8 + 2048 * i]);
            gl2lds16(Bt + boff[i] + k0, &S[8192 + tid * 8 + 2048 * i]);
        }
        __syncthreads();
#pragma unroll
        for (int ks = 0; ks < 2; ks++) {
            int kx = ((ks * 4 + q) ^ sw) * 8;
            bf16x8 af[4], bf[4];
#pragma unroll
            for (int i = 0; i < 4; i++)
                af[i] = *(const bf16x8*)&S[(wr * 64 + i * 16 + fr) * 64 + kx];
#pragma unroll
            for (int j = 0; j < 4; j++)
                bf[j] = *(const bf16x8*)&S[8192 + (wc * 64 + j * 16 + fr) * 64 + kx];
#pragma unroll
            for (int i = 0; i < 4; i++)
#pragma unroll
                for (int j = 0; j < 4; j++)
                    acc[i][j] = mfma16(af[i], bf[j], acc[i][j]);
        }
        __syncthreads();
    }

    int cc = lane & 15, r4 = q * 4;
#pragma unroll
    for (int i = 0; i < 4; i++)
#pragma unroll
        for (int j = 0; j < 4; j++) {
            int gn = n0 + wc * 64 + j * 16 + cc;
            if (gn >= DDIM) continue;
#pragma unroll
            for (int r = 0; r < 4; r++) {
                int gm = m0 + wr * 64 + i * 16 + r4 + r;
                if (gm < N_NODES) C[(size_t)gm * KP + gn] = f2b(acc[i][j][r]);
            }
        }
}

// ---------------------------------------------------------------------------
// Fused GRU, stacked-K: r,z over K=2048=[agg|h]; i_n first half, h_n second.
// Tile 128 rows x 64 gate-cols, BK=128, 4-bit XOR swizzle, LDS 80 KB.
// wcat = [3][1024][2048]; slabs r,z,n; cols 0:1024 = w_ih, 1024:2048 = w_hh.
// Per barrier-step: 20 DMA issues/thread, 96 MFMA/wave. acc = 128 f32/thread.
// 16 barrier-steps total (8 per phase) — per-barrier work is the lever.
// ---------------------------------------------------------------------------
__global__ __launch_bounds__(256) void gru_fused(const u16* __restrict__ agg,
                                                 const u16* __restrict__ h,
                                                 const u16* __restrict__ wcat,
                                                 const float* __restrict__ bih,
                                                 const float* __restrict__ bhh,
                                                 u16* __restrict__ hout) {
    __shared__ u16 S[40960];   // A[128][128]@0, W0@16384, W1@24576, W2@32768
    int tid = threadIdx.x;
    int lane = tid & 63, wave = tid >> 6;
    int wr = wave >> 1, wc = wave & 1;

    int bid = blockIdx.x;                 // grid 2512 = 8 xcd x 314
    int xcd = bid & 7;
    int s = bid >> 3;                     // 0..313
    int hi = (s >= 157) ? 1 : 0;
    int m0 = (s - hi * 157) * 128;
    int n0 = (xcd * 2 + hi) * 64;

    // staging maps (4-bit XOR): slot c (row=c>>4, sl=c&15), kc = sl^(row&15)
    int aoff[8], woff[4];
#pragma unroll
    for (int i = 0; i < 8; i++) {
        int c = tid + 256 * i;            // 0..2047: A rows 0..127, 16 chunks
        int row = c >> 4, sl = c & 15;
        int kc = sl ^ (row & 15);
        aoff[i] = (m0 + row) * KP + kc * 8;
    }
#pragma unroll
    for (int i = 0; i < 4; i++) {
        int c = tid + 256 * i;            // 0..1023: W rows 0..63, 16 chunks
        int row = c >> 4, sl = c & 15;
        int kc = sl ^ (row & 15);
        woff[i] = (n0 + row) * 2048 + kc * 8;
    }
    f32x4 aR[4][2] = {}, aZ[4][2] = {}, aN[4][2] = {}, aH[4][2] = {};
    int fr = lane & 15, q = lane >> 4;

#define GRU_PHASE(APTR, K0W, AN)                                              \
    for (int kk = 0; kk < 8; kk++) {                                          \
        int ka = kk * 128, kw = K0W + kk * 128;                               \
        _Pragma("unroll")                                                     \
        for (int i = 0; i < 8; i++)                                           \
            gl2lds16(APTR + aoff[i] + ka, &S[tid * 8 + 2048 * i]);            \
        _Pragma("unroll")                                                     \
        for (int i = 0; i < 4; i++) {                                         \
            gl2lds16(wcat + woff[i] + kw,                                     \
                     &S[16384 + tid * 8 + 2048 * i]);                         \
            gl2lds16(wcat + 2097152 + woff[i] + kw,                           \
                     &S[24576 + tid * 8 + 2048 * i]);                         \
            gl2lds16(wcat + 4194304 + woff[i] + kw,                           \
                     &S[32768 + tid * 8 + 2048 * i]);                         \
        }                                                                     \
        __syncthreads();                                                      \
        _Pragma("unroll")                                                     \
        for (int ks = 0; ks < 4; ks++) {                                      \
            int kx = ((ks * 4 + q) ^ fr) * 8;                                 \
            bf16x8 aa[4], w0[2], w1[2], w2[2];                                \
            _Pragma("unroll")                                                 \
            for (int i = 0; i < 4; i++)                                       \
                aa[i] = *(const bf16x8*)&S[(wr * 64 + i * 16 + fr) * 128 + kx];\
            _Pragma("unroll")                                                 \
            for (int j = 0; j < 2; j++) {                                     \
                int rb = (wc * 32 + j * 16 + fr) * 128 + kx;                  \
                w0[j] = *(const bf16x8*)&S[16384 + rb];                       \
                w1[j] = *(const bf16x8*)&S[24576 + rb];                       \
                w2[j] = *(const bf16x8*)&S[32768 + rb];                       \
            }                                                                 \
            _Pragma("unroll")                                                 \
            for (int i = 0; i < 4; i++)                                       \
                _Pragma("unroll")                                             \
                for (int j = 0; j < 2; j++) {                                 \
                    aR[i][j] = mfma16(aa[i], w0[j], aR[i][j]);                \
                    aZ[i][j] = mfma16(aa[i], w1[j], aZ[i][j]);                \
                    AN[i][j] = mfma16(aa[i], w2[j], AN[i][j]);                \
                }                                                             \
        }                                                                     \
        __syncthreads();                                                      \
    }

    GRU_PHASE(agg, 0, aN)      // k 0..1023:    agg vs w_ih -> r, z, i_n
    GRU_PHASE(h, 1024, aH)     // k 1024..2047: h   vs w_hh -> r, z, h_n
#undef GRU_PHASE

    int cc = lane & 15, r4 = q * 4;
#pragma unroll
    for (int j = 0; j < 2; j++) {
        int gn = n0 + wc * 32 + j * 16 + cc;
        if (gn >= DDIM) continue;
        float br  = bih[gn] + bhh[gn];
        float bz  = bih[1000 + gn] + bhh[1000 + gn];
        float bni = bih[2000 + gn];
        float bnh = bhh[2000 + gn];
#pragma unroll
        for (int i = 0; i < 4; i++)
#pragma unroll
            for (int r = 0; r < 4; r++) {
                int gm = m0 + wr * 64 + i * 16 + r4 + r;
                if (gm >= N_NODES) continue;
                float rg = sigmoidf_(aR[i][j][r] + br);
                float zg = sigmoidf_(aZ[i][j][r] + bz);
                float ng = tanhf(aN[i][j][r] + bni + rg * (aH[i][j][r] + bnh));
                size_t idx = (size_t)gm * KP + gn;
                float hp = b2f(h[idx]);
                hout[idx] = f2b((1.0f - zg) * ng + zg * hp);
            }
    }
}

// ---------------------------------------------------------------------------
// out[row] (fp32) = relu(h[row]) . fc_w + fc_b — one wave per row
// ---------------------------------------------------------------------------
__global__ __launch_bounds__(256) void fc_out(const u16* __restrict__ h,
                                              const float* __restrict__ fw,
                                              const float* __restrict__ fb,
                                              float* __restrict__ out) {
    int row = blockIdx.x * 4 + (threadIdx.x >> 6);
    int lane = threadIdx.x & 63;
    if (row >= N_NODES) return;
    float s = 0.0f;
    for (int i = 0; i < 4; i++) {
        int c = lane + 64 * i;
        if (c < 250) {
            uint2 v = *(const uint2*)(h + (size_t)row * KP + c * 4);
            float4 w = *(const float4*)(fw + c * 4);
            const u16* pv = (const u16*)&v;
            float h0 = b2f(pv[0]), h1 = b2f(pv[1]), h2 = b2f(pv[2]), h3 = b2f(pv[3]);
            s += (h0 > 0.0f ? h0 : 0.0f) * w.x;
            s += (h1 > 0.0f ? h1 : 0.0f) * w.y;
            s += (h2 > 0.0f ? h2 : 0.0f) * w.z;
            s += (h3 > 0.0f ? h3 : 0.0f) * w.w;
        }
    }
    for (int off = 32; off > 0; off >>= 1) s += __shfl_down(s, off, 64);
    if (lane == 0) out[row] = s + fb[0];
}

// ---------------------------------------------------------------------------
extern "C" void kernel_launch(void* const* d_in, const int* in_sizes, int n_in,
                              void* d_out, int out_size, void* d_ws, size_t ws_size,
                              hipStream_t stream) {
    const float* x   = (const float*)d_in[0];
    const int*   ei  = (const int*)d_in[1];
    const float* ew  = (const float*)d_in[2];
    const float* W   = (const float*)d_in[3];
    const float* wih = (const float*)d_in[4];
    const float* whh = (const float*)d_in[5];
    const float* bih = (const float*)d_in[6];
    const float* bhh = (const float*)d_in[7];
    const float* fw  = (const float*)d_in[8];
    const float* fb  = (const float*)d_in[9];
    float* out = (float*)d_out;

    // workspace (~144 MB)
    char* ws = (char*)d_ws;
    u16* xb   = (u16*)(ws);                    // [20000+][1024] bf16
    u16* bufA = (u16*)(ws + (size_t)SP);
    u16* bufB = (u16*)(ws + (size_t)2 * SP);   // agg
    u16* Wt   = (u16*)(ws + 123600000);        // 6.3 MB [3][1024][1024]
    u16* wcat = (u16*)(ws + 130000000);        // 12.6 MB [3][1024][2048]
    int* cnt  = (int*)(ws + 143000000);        // 80 KB
    int* cur  = (int*)(ws + 143100000);        // 80 KB
    int* ofs  = (int*)(ws + 143200000);        // 80 KB + 4
    int* bkt  = (int*)(ws + 143300096);        // 640 KB

    // one-time conversions + CSR build
    cvt_rows<<<N_NODES, 256, 0, stream>>>(x, xb);
    cvt_wcat<<<3000, 256, 0, stream>>>(wih, whh, wcat);
    transpose_w<<<dim3(32, 32, 3), dim3(32, 8), 0, stream>>>(W, Wt);
    hipMemsetAsync(cnt, 0, 80000, stream);
    hipMemsetAsync(cur, 0, 80000, stream);
    count_edges<<<625, 256, 0, stream>>>(ei, cnt);
    scan_offsets<<<1, 1024, 0, stream>>>(cnt, ofs);
    fill_buckets<<<625, 256, 0, stream>>>(ei, ofs, cur, bkt);

    // layer 0: h = xb; m -> bufA; agg -> bufB; h1 -> bufA (m dead)
    gemm_bt<<<1256, 256, 0, stream>>>(xb, Wt, bufA);
    node_agg<<<N_NODES, 256, 0, stream>>>(ei, ew, ofs, bkt, bufA, bufB);
    gru_fused<<<2512, 256, 0, stream>>>(bufB, xb, wcat, bih, bhh, bufA);

    // layer 1: h = bufA; m -> xb; agg -> bufB; h2 -> xb
    gemm_bt<<<1256, 256, 0, stream>>>(bufA, Wt + 1048576, xb);
    node_agg<<<N_NODES, 256, 0, stream>>>(ei, ew, ofs, bkt, xb, bufB);
    gru_fused<<<2512, 256, 0, stream>>>(bufB, bufA, wcat, bih, bhh, xb);

    // layer 2: h = xb; m -> bufA; agg -> bufB; h3 -> bufA
    gemm_bt<<<1256, 256, 0, stream>>>(xb, Wt + 2097152, bufA);
    node_agg<<<N_NODES, 256, 0, stream>>>(ei, ew, ofs, bkt, bufA, bufB);
    gru_fused<<<2512, 256, 0, stream>>>(bufB, xb, wcat, bih, bhh, bufA);

    // out = relu(h3) @ fc_w^T + fc_b
    fc_out<<<5000, 256, 0, stream>>>(bufA, fw, fb, out);
}

// Round 10
// 1360.925 us; speedup vs baseline: 1.5709x; 1.5709x over previous
//
#include <hip/hip_runtime.h>

typedef unsigned short u16;
typedef unsigned int u32;
typedef __attribute__((ext_vector_type(8))) short bf16x8;
typedef __attribute__((ext_vector_type(4))) float f32x4;

#define N_NODES 20000
#define N_EDGES 160000
#define DDIM    1000
#define KP      1024            // padded K / row stride (elements)
#define SP      41200000        // node-buffer spacing (bytes)
#define WCAT_L  6291456         // per-layer wcat elems = 3*1024*2048

__device__ __forceinline__ float b2f(u16 u) {
    union { u32 i; float f; } v; v.i = ((u32)u) << 16; return v.f;
}
__device__ __forceinline__ u16 f2b(float f) {
    union { float f; u32 i; } v; v.f = f;
    u32 r = v.i + 0x7FFFu + ((v.i >> 16) & 1u);
    return (u16)(r >> 16);
}
__device__ __forceinline__ u32 pack2(float a, float b) {
    return (u32)f2b(a) | ((u32)f2b(b) << 16);
}
__device__ __forceinline__ f32x4 mfma16(bf16x8 a, bf16x8 b, f32x4 c) {
    return __builtin_amdgcn_mfma_f32_16x16x32_bf16(a, b, c, 0, 0, 0);
}
__device__ __forceinline__ float sigmoidf_(float x) { return 1.0f / (1.0f + expf(-x)); }

// async global->LDS DMA, 16 B per lane; lds dest = wave-uniform base + lane*16
__device__ __forceinline__ void gl2lds16(const u16* g, u16* l) {
    __builtin_amdgcn_global_load_lds(
        (const __attribute__((address_space(1))) u32*)g,
        (__attribute__((address_space(3))) u32*)l, 16, 0, 0);
}

// ---------------------------------------------------------------------------
// fp32 [rows][1000] -> bf16 [rows][1024], zero-padded cols. One block per row.
// ---------------------------------------------------------------------------
__global__ __launch_bounds__(256) void cvt_rows(const float* __restrict__ in,
                                                u16* __restrict__ out) {
    int r = blockIdx.x, c = threadIdx.x * 4;
    u32 o[2] = {0, 0};
    if (c < DDIM) {
        float4 v = *(const float4*)(in + (size_t)r * DDIM + c);
        o[0] = pack2(v.x, v.y); o[1] = pack2(v.z, v.w);
    }
    *(uint2*)(out + (size_t)r * KP + c) = *(const uint2*)o;
}

// ---------------------------------------------------------------------------
// W[l] fp32 [1000][1000] -> Wb3 bf16 [l][1024(row pad unwritten)][1024]
// grid (1000, 3)
// ---------------------------------------------------------------------------
__global__ __launch_bounds__(256) void cvt_wb3(const float* __restrict__ W,
                                               u16* __restrict__ Wb3) {
    int r = blockIdx.x, l = blockIdx.y, c = threadIdx.x * 4;
    const float* in = W + (size_t)l * 1000000 + (size_t)r * DDIM;
    u32 o[2] = {0, 0};
    if (c < DDIM) {
        float4 v = *(const float4*)(in + c);
        o[0] = pack2(v.x, v.y); o[1] = pack2(v.z, v.w);
    }
    *(uint2*)(Wb3 + (size_t)l * 1048576 + (size_t)r * KP + c) = *(const uint2*)o;
}

// ---------------------------------------------------------------------------
// whh fp32 [3000][1000] -> phase-2 half of every layer's wcat:
// wcat_l[g][n][1024+c] = bf16(whh[g*1000+n][c]).  grid (3000, 3)
// ---------------------------------------------------------------------------
__global__ __launch_bounds__(256) void cvt_whh3(const float* __restrict__ whh,
                                                u16* __restrict__ wcat) {
    int r = blockIdx.x, l = blockIdx.y, c = threadIdx.x * 4;
    int g = r / 1000, n = r - g * 1000;
    u32 o[2] = {0, 0};
    if (c < DDIM) {
        float4 v = *(const float4*)(whh + (size_t)r * DDIM + c);
        o[0] = pack2(v.x, v.y); o[1] = pack2(v.z, v.w);
    }
    u16* dst = wcat + (size_t)l * WCAT_L + ((size_t)g * 1024 + n) * 2048 + 1024;
    *(uint2*)(dst + c) = *(const uint2*)o;
}

// ---------------------------------------------------------------------------
// CSR build (edge list constant): count -> scan -> fill
// ---------------------------------------------------------------------------
__global__ __launch_bounds__(256) void count_edges(const int* __restrict__ ei,
                                                   int* __restrict__ cnt) {
    int e = blockIdx.x * 256 + threadIdx.x;
    if (e < N_EDGES) atomicAdd(&cnt[ei[N_EDGES + e]], 1);
}

__global__ __launch_bounds__(1024) void scan_offsets(const int* __restrict__ cnt,
                                                     int* __restrict__ ofs) {
    __shared__ int s[1024];
    const int CH = 20;
    int t = threadIdx.x;
    int base = t * CH;
    int loc[CH];
    int sum = 0;
    for (int j = 0; j < CH; j++) {
        int i = base + j;
        loc[j] = sum;
        sum += (i < N_NODES) ? cnt[i] : 0;
    }
    s[t] = sum;
    __syncthreads();
    for (int d = 1; d < 1024; d <<= 1) {
        int v = (t >= d) ? s[t - d] : 0;
        __syncthreads();
        s[t] += v;
        __syncthreads();
    }
    int excl = s[t] - sum;
    for (int j = 0; j < CH; j++) {
        int i = base + j;
        if (i < N_NODES) ofs[i] = excl + loc[j];
    }
    if (t == 0) ofs[N_NODES] = N_EDGES;
}

__global__ __launch_bounds__(256) void fill_buckets(const int* __restrict__ ei,
                                                    const int* __restrict__ ofs,
                                                    int* __restrict__ cur,
                                                    int* __restrict__ bkt) {
    int e = blockIdx.x * 256 + threadIdx.x;
    if (e >= N_EDGES) return;
    int d = ei[N_EDGES + e];
    int pos = atomicAdd(&cur[d], 1);
    bkt[ofs[d] + pos] = e;
}

// ---------------------------------------------------------------------------
// t[node] = sum_{e: dst=node} h[src(e)] * ew[e] — one block/node, no atomics
// ---------------------------------------------------------------------------
__global__ __launch_bounds__(256) void node_agg(const int* __restrict__ ei,
                                                const float* __restrict__ ew,
                                                const int* __restrict__ ofs,
                                                const int* __restrict__ bkt,
                                                const u16* __restrict__ hsrc,
                                                u16* __restrict__ agg) {
    __shared__ int   s_src[64];
    __shared__ float s_w[64];
    int node = blockIdx.x;
    int t = threadIdx.x;                 // t<250 owns features [4t, 4t+4)
    int beg = ofs[node], end = ofs[node + 1];
    float4 acc = {0.f, 0.f, 0.f, 0.f};
    for (int cb = beg; cb < end; cb += 64) {
        int n = min(64, end - cb);
        if (t < n) {
            int e = bkt[cb + t];
            s_src[t] = ei[e];
            s_w[t]   = ew[e];
        }
        __syncthreads();
        if (t < 250) {
            for (int j = 0; j < n; j++) {
                int src = s_src[j];
                float w = s_w[j];
                uint2 v = *(const uint2*)(hsrc + (size_t)src * KP + t * 4);
                const u16* p = (const u16*)&v;
                acc.x += b2f(p[0]) * w;
                acc.y += b2f(p[1]) * w;
                acc.z += b2f(p[2]) * w;
                acc.w += b2f(p[3]) * w;
            }
        }
        __syncthreads();
    }
    if (t < 250) {
        u32 o[2] = {pack2(acc.x, acc.y), pack2(acc.z, acc.w)};
        *(uint2*)(agg + (size_t)node * KP + t * 4) = *(const uint2*)o;
    }
}

// ---------------------------------------------------------------------------
// Wc precompute: Wc_l[g, din] = sum_dout wihb[g][dout] * Wb3_l[din][dout]
// -> written into phase-1 half of wcat_l (slab = g/1000, row = g%1000).
// 128x128 tile, BK=64, XOR-swizzled staging. grid (192, 3).
// ---------------------------------------------------------------------------
__global__ __launch_bounds__(256) void gemm_wc(const u16* __restrict__ A,
                                               const u16* __restrict__ Bt3,
                                               u16* __restrict__ wcat) {
    __shared__ u16 S[16384];             // Sa [128][64] @0, Sb @8192 (u16 idx)
    int tid = threadIdx.x;
    int lane = tid & 63, wave = tid >> 6;
    int wr = wave >> 1, wc = wave & 1;
    int bid = blockIdx.x;
    int l = blockIdx.y;
    int m0 = (bid >> 3) * 128, n0 = (bid & 7) * 128;
    const u16* Bt = Bt3 + (size_t)l * 1048576;

    int aoff[4], boff[4];
#pragma unroll
    for (int i = 0; i < 4; i++) {
        int c = tid + 256 * i;
        int row = c >> 3, sl = c & 7;
        int kc = sl ^ (row & 7);
        aoff[i] = (m0 + row) * KP + kc * 8;
        boff[i] = (n0 + row) * KP + kc * 8;
    }
    f32x4 acc[4][4] = {};
    int fr = lane & 15, q = lane >> 4, sw = fr & 7;

    for (int k0 = 0; k0 < KP; k0 += 64) {
#pragma unroll
        for (int i = 0; i < 4; i++) {
            gl2lds16(A + aoff[i] + k0, &S[tid * 8 + 2048 * i]);
            gl2lds16(Bt + boff[i] + k0, &S[8192 + tid * 8 + 2048 * i]);
        }
        __syncthreads();
#pragma unroll
        for (int ks = 0; ks < 2; ks++) {
            int kx = ((ks * 4 + q) ^ sw) * 8;
            bf16x8 af[4], bf[4];
#pragma unroll
            for (int i = 0; i < 4; i++)
                af[i] = *(const bf16x8*)&S[(wr * 64 + i * 16 + fr) * 64 + kx];
#pragma unroll
            for (int j = 0; j < 4; j++)
                bf[j] = *(const bf16x8*)&S[8192 + (wc * 64 + j * 16 + fr) * 64 + kx];
#pragma unroll
            for (int i = 0; i < 4; i++)
#pragma unroll
                for (int j = 0; j < 4; j++)
                    acc[i][j] = mfma16(af[i], bf[j], acc[i][j]);
        }
        __syncthreads();
    }

    u16* wl = wcat + (size_t)l * WCAT_L;
    int cc = lane & 15, r4 = q * 4;
#pragma unroll
    for (int i = 0; i < 4; i++)
#pragma unroll
        for (int j = 0; j < 4; j++) {
            int gn = n0 + wc * 64 + j * 16 + cc;     // din column
            if (gn >= DDIM) continue;
#pragma unroll
            for (int r = 0; r < 4; r++) {
                int gm = m0 + wr * 64 + i * 16 + r4 + r;   // gate row 0..3071
                if (gm >= 3000) continue;
                int slab = (gm >= 2000) ? 2 : (gm >= 1000 ? 1 : 0);
                int row = gm - slab * 1000;
                wl[(size_t)slab * 2097152 + (size_t)row * 2048 + gn] =
                    f2b(acc[i][j][r]);
            }
        }
}

// ---------------------------------------------------------------------------
// Fused GRU, stacked-K: r,z over K=2048=[t|h]; i_n first half, h_n second.
// Tile 128 rows x 64 gate-cols, BK=64, XOR-swizzled staging, LDS 40 KB.
// wcat_l = [3][1024][2048]; slabs r,z,n; cols 0:1024 = Wc, 1024:2048 = w_hh.
// Per step: 10 DMA issues/thread, 48 MFMA/wave. acc = 128 f32/thread.  (R8)
// ---------------------------------------------------------------------------
__global__ __launch_bounds__(256) void gru_fused(const u16* __restrict__ agg,
                                                 const u16* __restrict__ h,
                                                 const u16* __restrict__ wcat,
                                                 const float* __restrict__ bih,
                                                 const float* __restrict__ bhh,
                                                 u16* __restrict__ hout) {
    __shared__ u16 S[20480];   // A[128][64]@0, W0@8192, W1@12288, W2@16384
    int tid = threadIdx.x;
    int lane = tid & 63, wave = tid >> 6;
    int wr = wave >> 1, wc = wave & 1;

    int bid = blockIdx.x;                 // grid 2512 = 8 xcd x 314
    int xcd = bid & 7;
    int s = bid >> 3;                     // 0..313
    int hi = (s >= 157) ? 1 : 0;
    int m0 = (s - hi * 157) * 128;
    int n0 = (xcd * 2 + hi) * 64;

    // staging maps (XOR swizzle): slot c (row=c>>3, sl=c&7), kc = sl^(row&7)
    int aoff[4], woff[2];
#pragma unroll
    for (int i = 0; i < 4; i++) {
        int c = tid + 256 * i;            // 0..1023: A rows 0..127
        int row = c >> 3, sl = c & 7;
        int kc = sl ^ (row & 7);
        aoff[i] = (m0 + row) * KP + kc * 8;
    }
#pragma unroll
    for (int i = 0; i < 2; i++) {
        int c = tid + 256 * i;            // 0..511: W rows 0..63
        int row = (c >> 3) & 63, sl = c & 7;
        int kc = sl ^ (row & 7);
        woff[i] = (n0 + row) * 2048 + kc * 8;
    }
    f32x4 aR[4][2] = {}, aZ[4][2] = {}, aN[4][2] = {}, aH[4][2] = {};
    int fr = lane & 15, q = lane >> 4, sw = fr & 7;

#define GRU_PHASE(APTR, K0W, AN)                                              \
    for (int kk = 0; kk < 16; kk++) {                                         \
        int ka = kk * 64, kw = K0W + kk * 64;                                 \
        _Pragma("unroll")                                                     \
        for (int i = 0; i < 4; i++)                                           \
            gl2lds16(APTR + aoff[i] + ka, &S[tid * 8 + 2048 * i]);            \
        _Pragma("unroll")                                                     \
        for (int i = 0; i < 2; i++) {                                         \
            gl2lds16(wcat + woff[i] + kw, &S[8192 + tid * 8 + 2048 * i]);     \
            gl2lds16(wcat + 2097152 + woff[i] + kw,                           \
                     &S[12288 + tid * 8 + 2048 * i]);                         \
            gl2lds16(wcat + 4194304 + woff[i] + kw,                           \
                     &S[16384 + tid * 8 + 2048 * i]);                         \
        }                                                                     \
        __syncthreads();                                                      \
        _Pragma("unroll")                                                     \
        for (int ks = 0; ks < 2; ks++) {                                      \
            int kx = ((ks * 4 + q) ^ sw) * 8;                                 \
            bf16x8 aa[4], w0[2], w1[2], w2[2];                                \
            _Pragma("unroll")                                                 \
            for (int i = 0; i < 4; i++)                                       \
                aa[i] = *(const bf16x8*)&S[(wr * 64 + i * 16 + fr) * 64 + kx];\
            _Pragma("unroll")                                                 \
            for (int j = 0; j < 2; j++) {                                     \
                int rb = (wc * 32 + j * 16 + fr) * 64 + kx;                   \
                w0[j] = *(const bf16x8*)&S[8192 + rb];                        \
                w1[j] = *(const bf16x8*)&S[12288 + rb];                       \
                w2[j] = *(const bf16x8*)&S[16384 + rb];                       \
            }                                                                 \
            _Pragma("unroll")                                                 \
            for (int i = 0; i < 4; i++)                                       \
                _Pragma("unroll")                                             \
                for (int j = 0; j < 2; j++) {                                 \
                    aR[i][j] = mfma16(aa[i], w0[j], aR[i][j]);                \
                    aZ[i][j] = mfma16(aa[i], w1[j], aZ[i][j]);                \
                    AN[i][j] = mfma16(aa[i], w2[j], AN[i][j]);                \
                }                                                             \
        }                                                                     \
        __syncthreads();                                                      \
    }

    GRU_PHASE(agg, 0, aN)      // k 0..1023:    t vs Wc    -> r, z, i_n
    GRU_PHASE(h, 1024, aH)     // k 1024..2047: h vs w_hh  -> r, z, h_n
#undef GRU_PHASE

    int cc = lane & 15, r4 = q * 4;
#pragma unroll
    for (int j = 0; j < 2; j++) {
        int gn = n0 + wc * 32 + j * 16 + cc;
        if (gn >= DDIM) continue;
        float br  = bih[gn] + bhh[gn];
        float bz  = bih[1000 + gn] + bhh[1000 + gn];
        float bni = bih[2000 + gn];
        float bnh = bhh[2000 + gn];
#pragma unroll
        for (int i = 0; i < 4; i++)
#pragma unroll
            for (int r = 0; r < 4; r++) {
                int gm = m0 + wr * 64 + i * 16 + r4 + r;
                if (gm >= N_NODES) continue;
                float rg = sigmoidf_(aR[i][j][r] + br);
                float zg = sigmoidf_(aZ[i][j][r] + bz);
                float ng = tanhf(aN[i][j][r] + bni + rg * (aH[i][j][r] + bnh));
                size_t idx = (size_t)gm * KP + gn;
                float hp = b2f(h[idx]);
                hout[idx] = f2b((1.0f - zg) * ng + zg * hp);
            }
    }
}

// ---------------------------------------------------------------------------
// out[row] (fp32) = relu(h[row]) . fc_w + fc_b — one wave per row
// ---------------------------------------------------------------------------
__global__ __launch_bounds__(256) void fc_out(const u16* __restrict__ h,
                                              const float* __restrict__ fw,
                                              const float* __restrict__ fb,
                                              float* __restrict__ out) {
    int row = blockIdx.x * 4 + (threadIdx.x >> 6);
    int lane = threadIdx.x & 63;
    if (row >= N_NODES) return;
    float s = 0.0f;
    for (int i = 0; i < 4; i++) {
        int c = lane + 64 * i;
        if (c < 250) {
            uint2 v = *(const uint2*)(h + (size_t)row * KP + c * 4);
            float4 w = *(const float4*)(fw + c * 4);
            const u16* pv = (const u16*)&v;
            float h0 = b2f(pv[0]), h1 = b2f(pv[1]), h2 = b2f(pv[2]), h3 = b2f(pv[3]);
            s += (h0 > 0.0f ? h0 : 0.0f) * w.x;
            s += (h1 > 0.0f ? h1 : 0.0f) * w.y;
            s += (h2 > 0.0f ? h2 : 0.0f) * w.z;
            s += (h3 > 0.0f ? h3 : 0.0f) * w.w;
        }
    }
    for (int off = 32; off > 0; off >>= 1) s += __shfl_down(s, off, 64);
    if (lane == 0) out[row] = s + fb[0];
}

// ---------------------------------------------------------------------------
extern "C" void kernel_launch(void* const* d_in, const int* in_sizes, int n_in,
                              void* d_out, int out_size, void* d_ws, size_t ws_size,
                              hipStream_t stream) {
    const float* x   = (const float*)d_in[0];
    const int*   ei  = (const int*)d_in[1];
    const float* ew  = (const float*)d_in[2];
    const float* W   = (const float*)d_in[3];
    const float* wih = (const float*)d_in[4];
    const float* whh = (const float*)d_in[5];
    const float* bih = (const float*)d_in[6];
    const float* bhh = (const float*)d_in[7];
    const float* fw  = (const float*)d_in[8];
    const float* fb  = (const float*)d_in[9];
    float* out = (float*)d_out;

    // workspace (~163 MB)
    char* ws = (char*)d_ws;
    u16* xb   = (u16*)(ws);                    // [20096][1024] bf16
    u16* bufA = (u16*)(ws + (size_t)SP);       // h rotation / setup scratch
    u16* bufB = (u16*)(ws + (size_t)2 * SP);   // t (aggregate)
    u16* wcat = (u16*)(ws + 123600000);        // 37.75 MB [3][3][1024][2048]
    int* cnt  = (int*)(ws + 161400000);        // 80 KB
    int* cur  = (int*)(ws + 161500000);        // 80 KB
    int* ofs  = (int*)(ws + 161600000);        // 80 KB + 4
    int* bkt  = (int*)(ws + 161700096);        // 640 KB

    // setup scratch inside bufA (free until layer-0 gru output)
    u16* wihb = bufA;                          // [3072][1024] (rows>=3000 junk ok)
    u16* Wb3  = bufA + 3145728;                // [3][1024][1024] (rows>=1000 junk ok)

    // one-time conversions + Wc precompute + CSR build
    cvt_rows<<<N_NODES, 256, 0, stream>>>(x, xb);
    cvt_rows<<<3000, 256, 0, stream>>>(wih, wihb);          // stride KP fits [3072][1024]
    cvt_wb3<<<dim3(1000, 3), 256, 0, stream>>>(W, Wb3);
    hipMemsetAsync(wcat, 0, (size_t)3 * WCAT_L * 2, stream);
    gemm_wc<<<dim3(192, 3), 256, 0, stream>>>(wihb, Wb3, wcat);
    cvt_whh3<<<dim3(3000, 3), 256, 0, stream>>>(whh, wcat);
    hipMemsetAsync(cnt, 0, 80000, stream);
    hipMemsetAsync(cur, 0, 80000, stream);
    count_edges<<<625, 256, 0, stream>>>(ei, cnt);
    scan_offsets<<<1, 1024, 0, stream>>>(cnt, ofs);
    fill_buckets<<<625, 256, 0, stream>>>(ei, ofs, cur, bkt);

    // layer 0: t = S*x -> bufB; h1 = GRU(t, xb, wcat0) -> bufA
    node_agg<<<N_NODES, 256, 0, stream>>>(ei, ew, ofs, bkt, xb, bufB);
    gru_fused<<<2512, 256, 0, stream>>>(bufB, xb, wcat, bih, bhh, bufA);

    // layer 1: t = S*h1 -> bufB; h2 = GRU(t, bufA, wcat1) -> xb
    node_agg<<<N_NODES, 256, 0, stream>>>(ei, ew, ofs, bkt, bufA, bufB);
    gru_fused<<<2512, 256, 0, stream>>>(bufB, bufA, wcat + WCAT_L, bih, bhh, xb);

    // layer 2: t = S*h2 -> bufB; h3 = GRU(t, xb, wcat2) -> bufA
    node_agg<<<N_NODES, 256, 0, stream>>>(ei, ew, ofs, bkt, xb, bufB);
    gru_fused<<<2512, 256, 0, stream>>>(bufB, xb, wcat + 2 * WCAT_L, bih, bhh, bufA);

    // out = relu(h3) @ fc_w^T + fc_b
    fc_out<<<5000, 256, 0, stream>>>(bufA, fw, fb, out);
}

// Round 11
// 1273.051 us; speedup vs baseline: 1.6793x; 1.0690x over previous
//
#include <hip/hip_runtime.h>

typedef unsigned short u16;
typedef unsigned int u32;
typedef __attribute__((ext_vector_type(8))) short bf16x8;
typedef __attribute__((ext_vector_type(4))) float f32x4;

#define N_NODES 20000
#define N_EDGES 160000
#define DDIM    1000
#define KP      1024            // padded K / row stride (elements)
#define SP      41200000        // node-buffer spacing (bytes)
#define WCAT_L  6291456         // per-layer wcat elems = 3*1024*2048

__device__ __forceinline__ float b2f(u16 u) {
    union { u32 i; float f; } v; v.i = ((u32)u) << 16; return v.f;
}
__device__ __forceinline__ u16 f2b(float f) {
    union { float f; u32 i; } v; v.f = f;
    u32 r = v.i + 0x7FFFu + ((v.i >> 16) & 1u);
    return (u16)(r >> 16);
}
__device__ __forceinline__ u32 pack2(float a, float b) {
    return (u32)f2b(a) | ((u32)f2b(b) << 16);
}
__device__ __forceinline__ f32x4 mfma16(bf16x8 a, bf16x8 b, f32x4 c) {
    return __builtin_amdgcn_mfma_f32_16x16x32_bf16(a, b, c, 0, 0, 0);
}
// fast transcendentals: v_exp_f32 / v_rcp_f32 (approx err << bf16 rounding)
__device__ __forceinline__ float fexp_(float x) {
    return __builtin_amdgcn_exp2f(x * 1.4426950408889634f);
}
__device__ __forceinline__ float fsigmoid_(float x) {
    return __builtin_amdgcn_rcpf(1.0f + fexp_(-x));   // x->-inf: rcp(inf)=0 ok
}
__device__ __forceinline__ float ftanh_(float x) {
    float ax = fabsf(x);
    float e = fexp_(-2.0f * ax);                       // e in (0,1], no overflow
    float t = (1.0f - e) * __builtin_amdgcn_rcpf(1.0f + e);
    return x >= 0.0f ? t : -t;
}

// async global->LDS DMA, 16 B per lane; lds dest = wave-uniform base + lane*16
__device__ __forceinline__ void gl2lds16(const u16* g, u16* l) {
    __builtin_amdgcn_global_load_lds(
        (const __attribute__((address_space(1))) u32*)g,
        (__attribute__((address_space(3))) u32*)l, 16, 0, 0);
}

// ---------------------------------------------------------------------------
// fp32 [rows][1000] -> bf16 [rows][1024], zero-padded cols. One block per row.
// ---------------------------------------------------------------------------
__global__ __launch_bounds__(256) void cvt_rows(const float* __restrict__ in,
                                                u16* __restrict__ out) {
    int r = blockIdx.x, c = threadIdx.x * 4;
    u32 o[2] = {0, 0};
    if (c < DDIM) {
        float4 v = *(const float4*)(in + (size_t)r * DDIM + c);
        o[0] = pack2(v.x, v.y); o[1] = pack2(v.z, v.w);
    }
    *(uint2*)(out + (size_t)r * KP + c) = *(const uint2*)o;
}

// ---------------------------------------------------------------------------
// W[l] fp32 [1000][1000] -> Wb3 bf16 [l][1024(row pad unwritten)][1024]
// grid (1000, 3)
// ---------------------------------------------------------------------------
__global__ __launch_bounds__(256) void cvt_wb3(const float* __restrict__ W,
                                               u16* __restrict__ Wb3) {
    int r = blockIdx.x, l = blockIdx.y, c = threadIdx.x * 4;
    const float* in = W + (size_t)l * 1000000 + (size_t)r * DDIM;
    u32 o[2] = {0, 0};
    if (c < DDIM) {
        float4 v = *(const float4*)(in + c);
        o[0] = pack2(v.x, v.y); o[1] = pack2(v.z, v.w);
    }
    *(uint2*)(Wb3 + (size_t)l * 1048576 + (size_t)r * KP + c) = *(const uint2*)o;
}

// ---------------------------------------------------------------------------
// whh fp32 [3000][1000] -> phase-2 half of every layer's wcat:
// wcat_l[g][n][1024+c] = bf16(whh[g*1000+n][c]); c>=1000 zero-padded.
// grid (3000, 3)
// ---------------------------------------------------------------------------
__global__ __launch_bounds__(256) void cvt_whh3(const float* __restrict__ whh,
                                                u16* __restrict__ wcat) {
    int r = blockIdx.x, l = blockIdx.y, c = threadIdx.x * 4;
    int g = r / 1000, n = r - g * 1000;
    u32 o[2] = {0, 0};
    if (c < DDIM) {
        float4 v = *(const float4*)(whh + (size_t)r * DDIM + c);
        o[0] = pack2(v.x, v.y); o[1] = pack2(v.z, v.w);
    }
    u16* dst = wcat + (size_t)l * WCAT_L + ((size_t)g * 1024 + n) * 2048 + 1024;
    *(uint2*)(dst + c) = *(const uint2*)o;
}

// ---------------------------------------------------------------------------
// CSR build (edge list constant): count -> scan -> fill
// ---------------------------------------------------------------------------
__global__ __launch_bounds__(256) void count_edges(const int* __restrict__ ei,
                                                   int* __restrict__ cnt) {
    int e = blockIdx.x * 256 + threadIdx.x;
    if (e < N_EDGES) atomicAdd(&cnt[ei[N_EDGES + e]], 1);
}

__global__ __launch_bounds__(1024) void scan_offsets(const int* __restrict__ cnt,
                                                     int* __restrict__ ofs) {
    __shared__ int s[1024];
    const int CH = 20;
    int t = threadIdx.x;
    int base = t * CH;
    int loc[CH];
    int sum = 0;
    for (int j = 0; j < CH; j++) {
        int i = base + j;
        loc[j] = sum;
        sum += (i < N_NODES) ? cnt[i] : 0;
    }
    s[t] = sum;
    __syncthreads();
    for (int d = 1; d < 1024; d <<= 1) {
        int v = (t >= d) ? s[t - d] : 0;
        __syncthreads();
        s[t] += v;
        __syncthreads();
    }
    int excl = s[t] - sum;
    for (int j = 0; j < CH; j++) {
        int i = base + j;
        if (i < N_NODES) ofs[i] = excl + loc[j];
    }
    if (t == 0) ofs[N_NODES] = N_EDGES;
}

__global__ __launch_bounds__(256) void fill_buckets(const int* __restrict__ ei,
                                                    const int* __restrict__ ofs,
                                                    int* __restrict__ cur,
                                                    int* __restrict__ bkt) {
    int e = blockIdx.x * 256 + threadIdx.x;
    if (e >= N_EDGES) return;
    int d = ei[N_EDGES + e];
    int pos = atomicAdd(&cur[d], 1);
    bkt[ofs[d] + pos] = e;
}

// ---------------------------------------------------------------------------
// t[node] = sum_{e: dst=node} h[src(e)] * ew[e] — one block/node, no atomics.
// Threads 250..255 zero the k-pad cols 1000..1023 (MFMA k-pad correctness:
// pad A zero x garbage W pad = 0; lets us skip the 75 MB wcat memset).
// ---------------------------------------------------------------------------
__global__ __launch_bounds__(256) void node_agg(const int* __restrict__ ei,
                                                const float* __restrict__ ew,
                                                const int* __restrict__ ofs,
                                                const int* __restrict__ bkt,
                                                const u16* __restrict__ hsrc,
                                                u16* __restrict__ agg) {
    __shared__ int   s_src[64];
    __shared__ float s_w[64];
    int node = blockIdx.x;
    int t = threadIdx.x;                 // t<250 owns features [4t, 4t+4)
    int beg = ofs[node], end = ofs[node + 1];
    float4 acc = {0.f, 0.f, 0.f, 0.f};
    for (int cb = beg; cb < end; cb += 64) {
        int n = min(64, end - cb);
        if (t < n) {
            int e = bkt[cb + t];
            s_src[t] = ei[e];
            s_w[t]   = ew[e];
        }
        __syncthreads();
        if (t < 250) {
            for (int j = 0; j < n; j++) {
                int src = s_src[j];
                float w = s_w[j];
                uint2 v = *(const uint2*)(hsrc + (size_t)src * KP + t * 4);
                const u16* p = (const u16*)&v;
                acc.x += b2f(p[0]) * w;
                acc.y += b2f(p[1]) * w;
                acc.z += b2f(p[2]) * w;
                acc.w += b2f(p[3]) * w;
            }
        }
        __syncthreads();
    }
    if (t < 250) {
        u32 o[2] = {pack2(acc.x, acc.y), pack2(acc.z, acc.w)};
        *(uint2*)(agg + (size_t)node * KP + t * 4) = *(const uint2*)o;
    } else {                             // zero pad cols 1000..1023
        uint2 z = {0, 0};
        *(uint2*)(agg + (size_t)node * KP + 1000 + (t - 250) * 4) = z;
    }
}

// ---------------------------------------------------------------------------
// Wc precompute: Wc_l[g, din] = sum_dout wihb[g][dout] * Wb3_l[din][dout]
// -> written into phase-1 half of wcat_l (slab = g/1000, row = g%1000).
// 128x128 tile, BK=64, XOR-swizzled staging. grid (192, 3).
// ---------------------------------------------------------------------------
__global__ __launch_bounds__(256) void gemm_wc(const u16* __restrict__ A,
                                               const u16* __restrict__ Bt3,
                                               u16* __restrict__ wcat) {
    __shared__ u16 S[16384];             // Sa [128][64] @0, Sb @8192 (u16 idx)
    int tid = threadIdx.x;
    int lane = tid & 63, wave = tid >> 6;
    int wr = wave >> 1, wc = wave & 1;
    int bid = blockIdx.x;
    int l = blockIdx.y;
    int m0 = (bid >> 3) * 128, n0 = (bid & 7) * 128;
    const u16* Bt = Bt3 + (size_t)l * 1048576;

    int aoff[4], boff[4];
#pragma unroll
    for (int i = 0; i < 4; i++) {
        int c = tid + 256 * i;
        int row = c >> 3, sl = c & 7;
        int kc = sl ^ (row & 7);
        aoff[i] = (m0 + row) * KP + kc * 8;
        boff[i] = (n0 + row) * KP + kc * 8;
    }
    f32x4 acc[4][4] = {};
    int fr = lane & 15, q = lane >> 4, sw = fr & 7;

    for (int k0 = 0; k0 < KP; k0 += 64) {
#pragma unroll
        for (int i = 0; i < 4; i++) {
            gl2lds16(A + aoff[i] + k0, &S[tid * 8 + 2048 * i]);
            gl2lds16(Bt + boff[i] + k0, &S[8192 + tid * 8 + 2048 * i]);
        }
        __syncthreads();
#pragma unroll
        for (int ks = 0; ks < 2; ks++) {
            int kx = ((ks * 4 + q) ^ sw) * 8;
            bf16x8 af[4], bf[4];
#pragma unroll
            for (int i = 0; i < 4; i++)
                af[i] = *(const bf16x8*)&S[(wr * 64 + i * 16 + fr) * 64 + kx];
#pragma unroll
            for (int j = 0; j < 4; j++)
                bf[j] = *(const bf16x8*)&S[8192 + (wc * 64 + j * 16 + fr) * 64 + kx];
#pragma unroll
            for (int i = 0; i < 4; i++)
#pragma unroll
                for (int j = 0; j < 4; j++)
                    acc[i][j] = mfma16(af[i], bf[j], acc[i][j]);
        }
        __syncthreads();
    }

    u16* wl = wcat + (size_t)l * WCAT_L;
    int cc = lane & 15, r4 = q * 4;
#pragma unroll
    for (int i = 0; i < 4; i++)
#pragma unroll
        for (int j = 0; j < 4; j++) {
            int gn = n0 + wc * 64 + j * 16 + cc;     // din column
            if (gn >= DDIM) continue;
#pragma unroll
            for (int r = 0; r < 4; r++) {
                int gm = m0 + wr * 64 + i * 16 + r4 + r;   // gate row 0..3071
                if (gm >= 3000) continue;
                int slab = (gm >= 2000) ? 2 : (gm >= 1000 ? 1 : 0);
                int row = gm - slab * 1000;
                wl[(size_t)slab * 2097152 + (size_t)row * 2048 + gn] =
                    f2b(acc[i][j][r]);
            }
        }
}

// ---------------------------------------------------------------------------
// Fused GRU, stacked-K: r,z over K=2048=[t|h]; i_n first half, h_n second.
// Tile 128 rows x 64 gate-cols, BK=64, XOR-swizzled staging, LDS 40 KB.
// wcat_l = [3][1024][2048]; slabs r,z,n; cols 0:1024 = Wc, 1024:2048 = w_hh.
// Per step: 10 DMA issues/thread, 48 MFMA/wave. acc = 128 f32/thread.
// NOTE: this config sits at the register-file corner (128 arch + 128 acc =
// 256/wave x 2 waves = 512 = full SIMD file) — do not grow tile or frags.
// ---------------------------------------------------------------------------
__global__ __launch_bounds__(256) void gru_fused(const u16* __restrict__ agg,
                                                 const u16* __restrict__ h,
                                                 const u16* __restrict__ wcat,
                                                 const float* __restrict__ bih,
                                                 const float* __restrict__ bhh,
                                                 u16* __restrict__ hout) {
    __shared__ u16 S[20480];   // A[128][64]@0, W0@8192, W1@12288, W2@16384
    int tid = threadIdx.x;
    int lane = tid & 63, wave = tid >> 6;
    int wr = wave >> 1, wc = wave & 1;

    int bid = blockIdx.x;                 // grid 2512 = 8 xcd x 314
    int xcd = bid & 7;
    int s = bid >> 3;                     // 0..313
    int hi = (s >= 157) ? 1 : 0;
    int m0 = (s - hi * 157) * 128;
    int n0 = (xcd * 2 + hi) * 64;

    // staging maps (XOR swizzle): slot c (row=c>>3, sl=c&7), kc = sl^(row&7)
    int aoff[4], woff[2];
#pragma unroll
    for (int i = 0; i < 4; i++) {
        int c = tid + 256 * i;            // 0..1023: A rows 0..127
        int row = c >> 3, sl = c & 7;
        int kc = sl ^ (row & 7);
        aoff[i] = (m0 + row) * KP + kc * 8;
    }
#pragma unroll
    for (int i = 0; i < 2; i++) {
        int c = tid + 256 * i;            // 0..511: W rows 0..63
        int row = (c >> 3) & 63, sl = c & 7;
        int kc = sl ^ (row & 7);
        woff[i] = (n0 + row) * 2048 + kc * 8;
    }
    f32x4 aR[4][2] = {}, aZ[4][2] = {}, aN[4][2] = {}, aH[4][2] = {};
    int fr = lane & 15, q = lane >> 4, sw = fr & 7;

#define GRU_PHASE(APTR, K0W, AN)                                              \
    for (int kk = 0; kk < 16; kk++) {                                         \
        int ka = kk * 64, kw = K0W + kk * 64;                                 \
        _Pragma("unroll")                                                     \
        for (int i = 0; i < 4; i++)                                           \
            gl2lds16(APTR + aoff[i] + ka, &S[tid * 8 + 2048 * i]);            \
        _Pragma("unroll")                                                     \
        for (int i = 0; i < 2; i++) {                                         \
            gl2lds16(wcat + woff[i] + kw, &S[8192 + tid * 8 + 2048 * i]);     \
            gl2lds16(wcat + 2097152 + woff[i] + kw,                           \
                     &S[12288 + tid * 8 + 2048 * i]);                         \
            gl2lds16(wcat + 4194304 + woff[i] + kw,                           \
                     &S[16384 + tid * 8 + 2048 * i]);                         \
        }                                                                     \
        __syncthreads();                                                      \
        _Pragma("unroll")                                                     \
        for (int ks = 0; ks < 2; ks++) {                                      \
            int kx = ((ks * 4 + q) ^ sw) * 8;                                 \
            bf16x8 aa[4], w0[2], w1[2], w2[2];                                \
            _Pragma("unroll")                                                 \
            for (int i = 0; i < 4; i++)                                       \
                aa[i] = *(const bf16x8*)&S[(wr * 64 + i * 16 + fr) * 64 + kx];\
            _Pragma("unroll")                                                 \
            for (int j = 0; j < 2; j++) {                                     \
                int rb = (wc * 32 + j * 16 + fr) * 64 + kx;                   \
                w0[j] = *(const bf16x8*)&S[8192 + rb];                        \
                w1[j] = *(const bf16x8*)&S[12288 + rb];                       \
                w2[j] = *(const bf16x8*)&S[16384 + rb];                       \
            }                                                                 \
            _Pragma("unroll")                                                 \
            for (int i = 0; i < 4; i++)                                       \
                _Pragma("unroll")                                             \
                for (int j = 0; j < 2; j++) {                                 \
                    aR[i][j] = mfma16(aa[i], w0[j], aR[i][j]);                \
                    aZ[i][j] = mfma16(aa[i], w1[j], aZ[i][j]);                \
                    AN[i][j] = mfma16(aa[i], w2[j], AN[i][j]);                \
                }                                                             \
        }                                                                     \
        __syncthreads();                                                      \
    }

    GRU_PHASE(agg, 0, aN)      // k 0..1023:    t vs Wc    -> r, z, i_n
    GRU_PHASE(h, 1024, aH)     // k 1024..2047: h vs w_hh  -> r, z, h_n
#undef GRU_PHASE

    int cc = lane & 15, r4 = q * 4;
#pragma unroll
    for (int j = 0; j < 2; j++) {
        int gn = n0 + wc * 32 + j * 16 + cc;
        if (gn >= DDIM) continue;
        float br  = bih[gn] + bhh[gn];
        float bz  = bih[1000 + gn] + bhh[1000 + gn];
        float bni = bih[2000 + gn];
        float bnh = bhh[2000 + gn];
#pragma unroll
        for (int i = 0; i < 4; i++)
#pragma unroll
            for (int r = 0; r < 4; r++) {
                int gm = m0 + wr * 64 + i * 16 + r4 + r;
                if (gm >= N_NODES) continue;
                float rg = fsigmoid_(aR[i][j][r] + br);
                float zg = fsigmoid_(aZ[i][j][r] + bz);
                float ng = ftanh_(aN[i][j][r] + bni + rg * (aH[i][j][r] + bnh));
                size_t idx = (size_t)gm * KP + gn;
                float hp = b2f(h[idx]);
                hout[idx] = f2b((1.0f - zg) * ng + zg * hp);
            }
    }
}

// ---------------------------------------------------------------------------
// out[row] (fp32) = relu(h[row]) . fc_w + fc_b — one wave per row
// ---------------------------------------------------------------------------
__global__ __launch_bounds__(256) void fc_out(const u16* __restrict__ h,
                                              const float* __restrict__ fw,
                                              const float* __restrict__ fb,
                                              float* __restrict__ out) {
    int row = blockIdx.x * 4 + (threadIdx.x >> 6);
    int lane = threadIdx.x & 63;
    if (row >= N_NODES) return;
    float s = 0.0f;
    for (int i = 0; i < 4; i++) {
        int c = lane + 64 * i;
        if (c < 250) {
            uint2 v = *(const uint2*)(h + (size_t)row * KP + c * 4);
            float4 w = *(const float4*)(fw + c * 4);
            const u16* pv = (const u16*)&v;
            float h0 = b2f(pv[0]), h1 = b2f(pv[1]), h2 = b2f(pv[2]), h3 = b2f(pv[3]);
            s += (h0 > 0.0f ? h0 : 0.0f) * w.x;
            s += (h1 > 0.0f ? h1 : 0.0f) * w.y;
            s += (h2 > 0.0f ? h2 : 0.0f) * w.z;
            s += (h3 > 0.0f ? h3 : 0.0f) * w.w;
        }
    }
    for (int off = 32; off > 0; off >>= 1) s += __shfl_down(s, off, 64);
    if (lane == 0) out[row] = s + fb[0];
}

// ---------------------------------------------------------------------------
extern "C" void kernel_launch(void* const* d_in, const int* in_sizes, int n_in,
                              void* d_out, int out_size, void* d_ws, size_t ws_size,
                              hipStream_t stream) {
    const float* x   = (const float*)d_in[0];
    const int*   ei  = (const int*)d_in[1];
    const float* ew  = (const float*)d_in[2];
    const float* W   = (const float*)d_in[3];
    const float* wih = (const float*)d_in[4];
    const float* whh = (const float*)d_in[5];
    const float* bih = (const float*)d_in[6];
    const float* bhh = (const float*)d_in[7];
    const float* fw  = (const float*)d_in[8];
    const float* fb  = (const float*)d_in[9];
    float* out = (float*)d_out;

    // workspace (~163 MB)
    char* ws = (char*)d_ws;
    u16* xb   = (u16*)(ws);                    // [20096][1024] bf16
    u16* bufA = (u16*)(ws + (size_t)SP);       // h rotation / setup scratch
    u16* bufB = (u16*)(ws + (size_t)2 * SP);   // t (aggregate)
    u16* wcat = (u16*)(ws + 123600000);        // 37.75 MB [3][3][1024][2048]
    int* cnt  = (int*)(ws + 161400000);        // 80 KB
    int* cur  = (int*)(ws + 161500000);        // 80 KB
    int* ofs  = (int*)(ws + 161600000);        // 80 KB + 4
    int* bkt  = (int*)(ws + 161700096);        // 640 KB

    // setup scratch inside bufA (free until layer-0 gru output)
    u16* wihb = bufA;                          // [3072][1024] (rows>=3000 junk ok)
    u16* Wb3  = bufA + 3145728;                // [3][1024][1024] (rows>=1000 junk ok)

    // one-time conversions + Wc precompute + CSR build.
    // No wcat memset: k-pad cols of valid outputs always multiply a ZERO A-pad
    // (cvt_rows / node_agg write zero pads; 0xAA poison is finite bf16), and
    // garbage weight ROWS feed only gn>=1000 outputs which epilogues discard.
    cvt_rows<<<N_NODES, 256, 0, stream>>>(x, xb);
    cvt_rows<<<3000, 256, 0, stream>>>(wih, wihb);          // stride KP fits [3072][1024]
    cvt_wb3<<<dim3(1000, 3), 256, 0, stream>>>(W, Wb3);
    gemm_wc<<<dim3(192, 3), 256, 0, stream>>>(wihb, Wb3, wcat);
    cvt_whh3<<<dim3(3000, 3), 256, 0, stream>>>(whh, wcat);
    hipMemsetAsync(cnt, 0, 80000, stream);
    hipMemsetAsync(cur, 0, 80000, stream);
    count_edges<<<625, 256, 0, stream>>>(ei, cnt);
    scan_offsets<<<1, 1024, 0, stream>>>(cnt, ofs);
    fill_buckets<<<625, 256, 0, stream>>>(ei, ofs, cur, bkt);

    // layer 0: t = S*x -> bufB; h1 = GRU(t, xb, wcat0) -> bufA
    node_agg<<<N_NODES, 256, 0, stream>>>(ei, ew, ofs, bkt, xb, bufB);
    gru_fused<<<2512, 256, 0, stream>>>(bufB, xb, wcat, bih, bhh, bufA);

    // layer 1: t = S*h1 -> bufB; h2 = GRU(t, bufA, wcat1) -> xb
    //   (h=bufA pad cols are poison but whh k-pad cols are zero -> safe)
    node_agg<<<N_NODES, 256, 0, stream>>>(ei, ew, ofs, bkt, bufA, bufB);
    gru_fused<<<2512, 256, 0, stream>>>(bufB, bufA, wcat + WCAT_L, bih, bhh, xb);

    // layer 2: t = S*h2 -> bufB; h3 = GRU(t, xb, wcat2) -> bufA
    node_agg<<<N_NODES, 256, 0, stream>>>(ei, ew, ofs, bkt, xb, bufB);
    gru_fused<<<2512, 256, 0, stream>>>(bufB, xb, wcat + 2 * WCAT_L, bih, bhh, bufA);

    // out = relu(h3) @ fc_w^T + fc_b
    fc_out<<<5000, 256, 0, stream>>>(bufA, fw, fb, out);
}

// Round 12
// 1271.946 us; speedup vs baseline: 1.6807x; 1.0009x over previous
//
#include <hip/hip_runtime.h>

typedef unsigned short u16;
typedef unsigned int u32;
typedef __attribute__((ext_vector_type(8))) short bf16x8;
typedef __attribute__((ext_vector_type(4))) float f32x4;

#define N_NODES 20000
#define N_EDGES 160000
#define DDIM    1000
#define KP      1024            // padded K / row stride (elements)
#define SP      41200000        // node-buffer spacing (bytes)
#define WCAT_L  6291456         // per-layer wcat elems = 3*1024*2048

__device__ __forceinline__ float b2f(u16 u) {
    union { u32 i; float f; } v; v.i = ((u32)u) << 16; return v.f;
}
__device__ __forceinline__ u16 f2b(float f) {
    union { float f; u32 i; } v; v.f = f;
    u32 r = v.i + 0x7FFFu + ((v.i >> 16) & 1u);
    return (u16)(r >> 16);
}
__device__ __forceinline__ u32 pack2(float a, float b) {
    return (u32)f2b(a) | ((u32)f2b(b) << 16);
}
__device__ __forceinline__ f32x4 mfma16(bf16x8 a, bf16x8 b, f32x4 c) {
    return __builtin_amdgcn_mfma_f32_16x16x32_bf16(a, b, c, 0, 0, 0);
}
// fast transcendentals: v_exp_f32 / v_rcp_f32 (approx err << bf16 rounding)
__device__ __forceinline__ float fexp_(float x) {
    return __builtin_amdgcn_exp2f(x * 1.4426950408889634f);
}
__device__ __forceinline__ float fsigmoid_(float x) {
    return __builtin_amdgcn_rcpf(1.0f + fexp_(-x));   // x->-inf: rcp(inf)=0 ok
}
__device__ __forceinline__ float ftanh_(float x) {
    float ax = fabsf(x);
    float e = fexp_(-2.0f * ax);                       // e in (0,1], no overflow
    float t = (1.0f - e) * __builtin_amdgcn_rcpf(1.0f + e);
    return x >= 0.0f ? t : -t;
}

// async global->LDS DMA, 16 B per lane; lds dest = wave-uniform base + lane*16
__device__ __forceinline__ void gl2lds16(const u16* g, u16* l) {
    __builtin_amdgcn_global_load_lds(
        (const __attribute__((address_space(1))) u32*)g,
        (__attribute__((address_space(3))) u32*)l, 16, 0, 0);
}

// ---------------------------------------------------------------------------
// fp32 [rows][1000] -> bf16 [rows][1024], zero-padded cols. One block per row.
// ---------------------------------------------------------------------------
__global__ __launch_bounds__(256) void cvt_rows(const float* __restrict__ in,
                                                u16* __restrict__ out) {
    int r = blockIdx.x, c = threadIdx.x * 4;
    u32 o[2] = {0, 0};
    if (c < DDIM) {
        float4 v = *(const float4*)(in + (size_t)r * DDIM + c);
        o[0] = pack2(v.x, v.y); o[1] = pack2(v.z, v.w);
    }
    *(uint2*)(out + (size_t)r * KP + c) = *(const uint2*)o;
}

// ---------------------------------------------------------------------------
// Merged weight conversions (one dispatch, grid 15000):
//   b in [0,3000):      wih row b        -> wihb [3072][1024] (stride KP)
//   b in [3000,6000):   W row (b-3000)   -> Wb3 [3][1024][1024]
//   b in [6000,15000):  whh row, layer l -> wcat_l phase-2 half (+1024)
// All k-pads (c>=1000) written zero.
// ---------------------------------------------------------------------------
__global__ __launch_bounds__(256) void cvt_weights(const float* __restrict__ wih,
                                                   const float* __restrict__ W,
                                                   const float* __restrict__ whh,
                                                   u16* __restrict__ wihb,
                                                   u16* __restrict__ Wb3,
                                                   u16* __restrict__ wcat) {
    int b = blockIdx.x, c = threadIdx.x * 4;
    const float* src;
    u16* dst;
    if (b < 3000) {
        src = wih + (size_t)b * DDIM;
        dst = wihb + (size_t)b * KP;
    } else if (b < 6000) {
        int r = b - 3000;                    // 0..2999 = l*1000 + row
        int l = r / 1000, row = r - l * 1000;
        src = W + (size_t)r * DDIM;
        dst = Wb3 + (size_t)l * 1048576 + (size_t)row * KP;
    } else {
        int r = b - 6000;                    // 0..8999: l = r/3000, gr = r%3000
        int l = r / 3000, gr = r - l * 3000;
        int g = gr / 1000, n2 = gr - g * 1000;
        src = whh + (size_t)gr * DDIM;
        dst = wcat + (size_t)l * WCAT_L + ((size_t)g * 1024 + n2) * 2048 + 1024;
    }
    u32 o[2] = {0, 0};
    if (c < DDIM) {
        float4 v = *(const float4*)(src + c);
        o[0] = pack2(v.x, v.y); o[1] = pack2(v.z, v.w);
    }
    *(uint2*)(dst + c) = *(const uint2*)o;
}

// ---------------------------------------------------------------------------
// CSR build (edge list constant): count -> scan -> fill
// ---------------------------------------------------------------------------
__global__ __launch_bounds__(256) void count_edges(const int* __restrict__ ei,
                                                   int* __restrict__ cnt) {
    int e = blockIdx.x * 256 + threadIdx.x;
    if (e < N_EDGES) atomicAdd(&cnt[ei[N_EDGES + e]], 1);
}

__global__ __launch_bounds__(1024) void scan_offsets(const int* __restrict__ cnt,
                                                     int* __restrict__ ofs) {
    __shared__ int s[1024];
    const int CH = 20;
    int t = threadIdx.x;
    int base = t * CH;
    int loc[CH];
    int sum = 0;
    for (int j = 0; j < CH; j++) {
        int i = base + j;
        loc[j] = sum;
        sum += (i < N_NODES) ? cnt[i] : 0;
    }
    s[t] = sum;
    __syncthreads();
    for (int d = 1; d < 1024; d <<= 1) {
        int v = (t >= d) ? s[t - d] : 0;
        __syncthreads();
        s[t] += v;
        __syncthreads();
    }
    int excl = s[t] - sum;
    for (int j = 0; j < CH; j++) {
        int i = base + j;
        if (i < N_NODES) ofs[i] = excl + loc[j];
    }
    if (t == 0) ofs[N_NODES] = N_EDGES;
}

__global__ __launch_bounds__(256) void fill_buckets(const int* __restrict__ ei,
                                                    const int* __restrict__ ofs,
                                                    int* __restrict__ cur,
                                                    int* __restrict__ bkt) {
    int e = blockIdx.x * 256 + threadIdx.x;
    if (e >= N_EDGES) return;
    int d = ei[N_EDGES + e];
    int pos = atomicAdd(&cur[d], 1);
    bkt[ofs[d] + pos] = e;
}

// ---------------------------------------------------------------------------
// t[node] = sum_{e: dst=node} h[src(e)] * ew[e] — TWO nodes per block
// (half = tid>>7), uint4 gathers (125 lanes x 16 B = one 2 KB row / edge).
// Sum order per element identical to the 1-node version (bitwise-same agg).
// Threads 125..127 of each half zero k-pad cols 1000..1023.
// ---------------------------------------------------------------------------
__global__ __launch_bounds__(256) void node_agg(const int* __restrict__ ei,
                                                const float* __restrict__ ew,
                                                const int* __restrict__ ofs,
                                                const int* __restrict__ bkt,
                                                const u16* __restrict__ hsrc,
                                                u16* __restrict__ agg) {
    __shared__ int   s_src[2][32];
    __shared__ float s_w[2][32];
    __shared__ int   s_it[2];
    int tid = threadIdx.x;
    int half = tid >> 7, t = tid & 127;
    int node = blockIdx.x * 2 + half;        // grid 10000 -> nodes 0..19999
    int beg = ofs[node], end = ofs[node + 1];
    if (t == 0) s_it[half] = (end - beg + 31) >> 5;
    __syncthreads();
    int iters = max(s_it[0], s_it[1]);
    float acc[8] = {};
    for (int it = 0; it < iters; it++) {
        int cb = beg + it * 32;
        int n = min(32, end - cb);           // may be <= 0 for the short half
        if (t < n) {
            int e = bkt[cb + t];
            s_src[half][t] = ei[e];
            s_w[half][t]   = ew[e];
        }
        __syncthreads();
        if (t < 125) {
            for (int j = 0; j < n; j++) {
                int src = s_src[half][j];
                float w = s_w[half][j];
                uint4 v = *(const uint4*)(hsrc + (size_t)src * KP + t * 8);
                const u16* p = (const u16*)&v;
#pragma unroll
                for (int k = 0; k < 8; k++) acc[k] += b2f(p[k]) * w;
            }
        }
        __syncthreads();
    }
    if (t < 125) {
        u32 o[4] = {pack2(acc[0], acc[1]), pack2(acc[2], acc[3]),
                    pack2(acc[4], acc[5]), pack2(acc[6], acc[7])};
        *(uint4*)(agg + (size_t)node * KP + t * 8) = *(const uint4*)o;
    } else if (t < 128) {                    // zero pad cols 1000..1023
        uint4 z = {0, 0, 0, 0};
        *(uint4*)(agg + (size_t)node * KP + 1000 + (t - 125) * 8) = z;
    }
}

// ---------------------------------------------------------------------------
// Wc precompute: Wc_l[g, din] = sum_dout wihb[g][dout] * Wb3_l[din][dout]
// -> written into phase-1 half of wcat_l (slab = g/1000, row = g%1000).
// 128x128 tile, BK=64, XOR-swizzled staging. grid (192, 3).
// ---------------------------------------------------------------------------
__global__ __launch_bounds__(256) void gemm_wc(const u16* __restrict__ A,
                                               const u16* __restrict__ Bt3,
                                               u16* __restrict__ wcat) {
    __shared__ u16 S[16384];             // Sa [128][64] @0, Sb @8192 (u16 idx)
    int tid = threadIdx.x;
    int lane = tid & 63, wave = tid >> 6;
    int wr = wave >> 1, wc = wave & 1;
    int bid = blockIdx.x;
    int l = blockIdx.y;
    int m0 = (bid >> 3) * 128, n0 = (bid & 7) * 128;
    const u16* Bt = Bt3 + (size_t)l * 1048576;

    int aoff[4], boff[4];
#pragma unroll
    for (int i = 0; i < 4; i++) {
        int c = tid + 256 * i;
        int row = c >> 3, sl = c & 7;
        int kc = sl ^ (row & 7);
        aoff[i] = (m0 + row) * KP + kc * 8;
        boff[i] = (n0 + row) * KP + kc * 8;
    }
    f32x4 acc[4][4] = {};
    int fr = lane & 15, q = lane >> 4, sw = fr & 7;

    for (int k0 = 0; k0 < KP; k0 += 64) {
#pragma unroll
        for (int i = 0; i < 4; i++) {
            gl2lds16(A + aoff[i] + k0, &S[tid * 8 + 2048 * i]);
            gl2lds16(Bt + boff[i] + k0, &S[8192 + tid * 8 + 2048 * i]);
        }
        __syncthreads();
#pragma unroll
        for (int ks = 0; ks < 2; ks++) {
            int kx = ((ks * 4 + q) ^ sw) * 8;
            bf16x8 af[4], bf[4];
#pragma unroll
            for (int i = 0; i < 4; i++)
                af[i] = *(const bf16x8*)&S[(wr * 64 + i * 16 + fr) * 64 + kx];
#pragma unroll
            for (int j = 0; j < 4; j++)
                bf[j] = *(const bf16x8*)&S[8192 + (wc * 64 + j * 16 + fr) * 64 + kx];
#pragma unroll
            for (int i = 0; i < 4; i++)
#pragma unroll
                for (int j = 0; j < 4; j++)
                    acc[i][j] = mfma16(af[i], bf[j], acc[i][j]);
        }
        __syncthreads();
    }

    u16* wl = wcat + (size_t)l * WCAT_L;
    int cc = lane & 15, r4 = q * 4;
#pragma unroll
    for (int i = 0; i < 4; i++)
#pragma unroll
        for (int j = 0; j < 4; j++) {
            int gn = n0 + wc * 64 + j * 16 + cc;     // din column
            if (gn >= DDIM) continue;
#pragma unroll
            for (int r = 0; r < 4; r++) {
                int gm = m0 + wr * 64 + i * 16 + r4 + r;   // gate row 0..3071
                if (gm >= 3000) continue;
                int slab = (gm >= 2000) ? 2 : (gm >= 1000 ? 1 : 0);
                int row = gm - slab * 1000;
                wl[(size_t)slab * 2097152 + (size_t)row * 2048 + gn] =
                    f2b(acc[i][j][r]);
            }
        }
}

// ---------------------------------------------------------------------------
// Fused GRU, stacked-K: r,z over K=2048=[t|h]; i_n first half, h_n second.
// Tile 128 rows x 64 gate-cols, BK=64, XOR-swizzled staging, LDS 40 KB.
// wcat_l = [3][1024][2048]; slabs r,z,n; cols 0:1024 = Wc, 1024:2048 = w_hh.
// Per step: 10 DMA issues/thread, 48 MFMA/wave. acc = 128 f32/thread.
// NOTE: register-file corner (128 arch + 128 acc = 256/wave x 2 waves = 512
// = full SIMD file) — do not grow tile or frags. BK=128 proved a 1-block/CU
// cliff (R9); explicit pipelining is structurally blocked (guide m99-m141).
// ---------------------------------------------------------------------------
__global__ __launch_bounds__(256) void gru_fused(const u16* __restrict__ agg,
                                                 const u16* __restrict__ h,
                                                 const u16* __restrict__ wcat,
                                                 const float* __restrict__ bih,
                                                 const float* __restrict__ bhh,
                                                 u16* __restrict__ hout) {
    __shared__ u16 S[20480];   // A[128][64]@0, W0@8192, W1@12288, W2@16384
    int tid = threadIdx.x;
    int lane = tid & 63, wave = tid >> 6;
    int wr = wave >> 1, wc = wave & 1;

    int bid = blockIdx.x;                 // grid 2512 = 8 xcd x 314
    int xcd = bid & 7;
    int s = bid >> 3;                     // 0..313
    int hi = (s >= 157) ? 1 : 0;
    int m0 = (s - hi * 157) * 128;
    int n0 = (xcd * 2 + hi) * 64;

    // staging maps (XOR swizzle): slot c (row=c>>3, sl=c&7), kc = sl^(row&7)
    int aoff[4], woff[2];
#pragma unroll
    for (int i = 0; i < 4; i++) {
        int c = tid + 256 * i;            // 0..1023: A rows 0..127
        int row = c >> 3, sl = c & 7;
        int kc = sl ^ (row & 7);
        aoff[i] = (m0 + row) * KP + kc * 8;
    }
#pragma unroll
    for (int i = 0; i < 2; i++) {
        int c = tid + 256 * i;            // 0..511: W rows 0..63
        int row = (c >> 3) & 63, sl = c & 7;
        int kc = sl ^ (row & 7);
        woff[i] = (n0 + row) * 2048 + kc * 8;
    }
    f32x4 aR[4][2] = {}, aZ[4][2] = {}, aN[4][2] = {}, aH[4][2] = {};
    int fr = lane & 15, q = lane >> 4, sw = fr & 7;

#define GRU_PHASE(APTR, K0W, AN)                                              \
    for (int kk = 0; kk < 16; kk++) {                                         \
        int ka = kk * 64, kw = K0W + kk * 64;                                 \
        _Pragma("unroll")                                                     \
        for (int i = 0; i < 4; i++)                                           \
            gl2lds16(APTR + aoff[i] + ka, &S[tid * 8 + 2048 * i]);            \
        _Pragma("unroll")                                                     \
        for (int i = 0; i < 2; i++) {                                         \
            gl2lds16(wcat + woff[i] + kw, &S[8192 + tid * 8 + 2048 * i]);     \
            gl2lds16(wcat + 2097152 + woff[i] + kw,                           \
                     &S[12288 + tid * 8 + 2048 * i]);                         \
            gl2lds16(wcat + 4194304 + woff[i] + kw,                           \
                     &S[16384 + tid * 8 + 2048 * i]);                         \
        }                                                                     \
        __syncthreads();                                                      \
        _Pragma("unroll")                                                     \
        for (int ks = 0; ks < 2; ks++) {                                      \
            int kx = ((ks * 4 + q) ^ sw) * 8;                                 \
            bf16x8 aa[4], w0[2], w1[2], w2[2];                                \
            _Pragma("unroll")                                                 \
            for (int i = 0; i < 4; i++)                                       \
                aa[i] = *(const bf16x8*)&S[(wr * 64 + i * 16 + fr) * 64 + kx];\
            _Pragma("unroll")                                                 \
            for (int j = 0; j < 2; j++) {                                     \
                int rb = (wc * 32 + j * 16 + fr) * 64 + kx;                   \
                w0[j] = *(const bf16x8*)&S[8192 + rb];                        \
                w1[j] = *(const bf16x8*)&S[12288 + rb];                       \
                w2[j] = *(const bf16x8*)&S[16384 + rb];                       \
            }                                                                 \
            _Pragma("unroll")                                                 \
            for (int i = 0; i < 4; i++)                                       \
                _Pragma("unroll")                                             \
                for (int j = 0; j < 2; j++) {                                 \
                    aR[i][j] = mfma16(aa[i], w0[j], aR[i][j]);                \
                    aZ[i][j] = mfma16(aa[i], w1[j], aZ[i][j]);                \
                    AN[i][j] = mfma16(aa[i], w2[j], AN[i][j]);                \
                }                                                             \
        }                                                                     \
        __syncthreads();                                                      \
    }

    GRU_PHASE(agg, 0, aN)      // k 0..1023:    t vs Wc    -> r, z, i_n
    GRU_PHASE(h, 1024, aH)     // k 1024..2047: h vs w_hh  -> r, z, h_n
#undef GRU_PHASE

    int cc = lane & 15, r4 = q * 4;
#pragma unroll
    for (int j = 0; j < 2; j++) {
        int gn = n0 + wc * 32 + j * 16 + cc;
        if (gn >= DDIM) continue;
        float br  = bih[gn] + bhh[gn];
        float bz  = bih[1000 + gn] + bhh[1000 + gn];
        float bni = bih[2000 + gn];
        float bnh = bhh[2000 + gn];
#pragma unroll
        for (int i = 0; i < 4; i++)
#pragma unroll
            for (int r = 0; r < 4; r++) {
                int gm = m0 + wr * 64 + i * 16 + r4 + r;
                if (gm >= N_NODES) continue;
                float rg = fsigmoid_(aR[i][j][r] + br);
                float zg = fsigmoid_(aZ[i][j][r] + bz);
                float ng = ftanh_(aN[i][j][r] + bni + rg * (aH[i][j][r] + bnh));
                size_t idx = (size_t)gm * KP + gn;
                float hp = b2f(h[idx]);
                hout[idx] = f2b((1.0f - zg) * ng + zg * hp);
            }
    }
}

// ---------------------------------------------------------------------------
// out[row] (fp32) = relu(h[row]) . fc_w + fc_b — one wave per row, uint4 loads
// ---------------------------------------------------------------------------
__global__ __launch_bounds__(256) void fc_out(const u16* __restrict__ h,
                                              const float* __restrict__ fw,
                                              const float* __restrict__ fb,
                                              float* __restrict__ out) {
    int row = blockIdx.x * 4 + (threadIdx.x >> 6);
    int lane = threadIdx.x & 63;
    if (row >= N_NODES) return;
    float s = 0.0f;
#pragma unroll
    for (int i = 0; i < 2; i++) {
        int c = lane + 64 * i;               // chunk of 8 elems
        if (c < 125) {
            uint4 v = *(const uint4*)(h + (size_t)row * KP + c * 8);
            const u16* pv = (const u16*)&v;
            float4 w0 = *(const float4*)(fw + c * 8);
            float4 w1 = *(const float4*)(fw + c * 8 + 4);
            const float* wp = (const float*)&w0;
            float hv;
#pragma unroll
            for (int k = 0; k < 4; k++) {
                hv = b2f(pv[k]);
                s += (hv > 0.0f ? hv : 0.0f) * wp[k];
            }
            wp = (const float*)&w1;
#pragma unroll
            for (int k = 0; k < 4; k++) {
                hv = b2f(pv[4 + k]);
                s += (hv > 0.0f ? hv : 0.0f) * wp[k];
            }
        }
    }
    for (int off = 32; off > 0; off >>= 1) s += __shfl_down(s, off, 64);
    if (lane == 0) out[row] = s + fb[0];
}

// ---------------------------------------------------------------------------
extern "C" void kernel_launch(void* const* d_in, const int* in_sizes, int n_in,
                              void* d_out, int out_size, void* d_ws, size_t ws_size,
                              hipStream_t stream) {
    const float* x   = (const float*)d_in[0];
    const int*   ei  = (const int*)d_in[1];
    const float* ew  = (const float*)d_in[2];
    const float* W   = (const float*)d_in[3];
    const float* wih = (const float*)d_in[4];
    const float* whh = (const float*)d_in[5];
    const float* bih = (const float*)d_in[6];
    const float* bhh = (const float*)d_in[7];
    const float* fw  = (const float*)d_in[8];
    const float* fb  = (const float*)d_in[9];
    float* out = (float*)d_out;

    // workspace (~163 MB)
    char* ws = (char*)d_ws;
    u16* xb   = (u16*)(ws);                    // [20096][1024] bf16
    u16* bufA = (u16*)(ws + (size_t)SP);       // h rotation / setup scratch
    u16* bufB = (u16*)(ws + (size_t)2 * SP);   // t (aggregate)
    u16* wcat = (u16*)(ws + 123600000);        // 37.75 MB [3][3][1024][2048]
    int* cnt  = (int*)(ws + 161400000);        // 80 KB   (cur adjacent)
    int* cur  = (int*)(ws + 161480000);        // 80 KB
    int* ofs  = (int*)(ws + 161560000);        // 80 KB + 4
    int* bkt  = (int*)(ws + 161640192);        // 640 KB

    // setup scratch inside bufA (free until layer-0 gru output)
    u16* wihb = bufA;                          // [3072][1024] (rows>=3000 junk ok)
    u16* Wb3  = bufA + 3145728;                // [3][1024][1024] (rows>=1000 junk ok)

    // one-time conversions + Wc precompute + CSR build.
    // No wcat memset: k-pad cols of valid outputs always multiply a ZERO A-pad
    // (cvt_rows / node_agg write zero pads; 0xAA poison is finite bf16), and
    // garbage weight ROWS feed only gn>=1000 outputs which epilogues discard.
    cvt_rows<<<N_NODES, 256, 0, stream>>>(x, xb);
    cvt_weights<<<15000, 256, 0, stream>>>(wih, W, whh, wihb, Wb3, wcat);
    gemm_wc<<<dim3(192, 3), 256, 0, stream>>>(wihb, Wb3, wcat);
    hipMemsetAsync(cnt, 0, 160000, stream);    // cnt + cur (contiguous)
    count_edges<<<625, 256, 0, stream>>>(ei, cnt);
    scan_offsets<<<1, 1024, 0, stream>>>(cnt, ofs);
    fill_buckets<<<625, 256, 0, stream>>>(ei, ofs, cur, bkt);

    // layer 0: t = S*x -> bufB; h1 = GRU(t, xb, wcat0) -> bufA
    node_agg<<<10000, 256, 0, stream>>>(ei, ew, ofs, bkt, xb, bufB);
    gru_fused<<<2512, 256, 0, stream>>>(bufB, xb, wcat, bih, bhh, bufA);

    // layer 1: t = S*h1 -> bufB; h2 = GRU(t, bufA, wcat1) -> xb
    node_agg<<<10000, 256, 0, stream>>>(ei, ew, ofs, bkt, bufA, bufB);
    gru_fused<<<2512, 256, 0, stream>>>(bufB, bufA, wcat + WCAT_L, bih, bhh, xb);

    // layer 2: t = S*h2 -> bufB; h3 = GRU(t, xb, wcat2) -> bufA
    node_agg<<<10000, 256, 0, stream>>>(ei, ew, ofs, bkt, xb, bufB);
    gru_fused<<<2512, 256, 0, stream>>>(bufB, xb, wcat + 2 * WCAT_L, bih, bhh, bufA);

    // out = relu(h3) @ fc_w^T + fc_b
    fc_out<<<5000, 256, 0, stream>>>(bufA, fw, fb, out);
}